// Round 1
// 290.408 us; speedup vs baseline: 1.7077x; 1.7077x over previous
//
#include <hip/hip_runtime.h>
#include <hip/hip_bf16.h>
#include <math.h>

#define B_     128
#define DIM_   512
#define HEADS_ 8
#define HD_    64
#define N_     196
#define NP_    224            // padded n (14 tiles of 16)
#define NROW_  208            // padded n rows (13 tiles of 16) for EB
#define SCALE_ 0.125f
#define BSTRIDE (DIM_ * N_)
#define J_     (B_ * NP_)     // 28672 GEMM columns (b*224+n)

typedef unsigned short u16;
typedef unsigned int   u32;
typedef __attribute__((ext_vector_type(8))) short bf16x8;   // 8 bf16 = 4 VGPRs
typedef __attribute__((ext_vector_type(4))) float f32x4;

__device__ __forceinline__ u16 f2bf(float f) {              // RNE fp32->bf16
    u32 u = __float_as_uint(f);
    return (u16)((u + 0x7fffu + ((u >> 16) & 1u)) >> 16);
}
__device__ __forceinline__ void gload_lds16(const u16* g, u16* l) {
    // async global->LDS, 16B/lane; LDS dest = wave-uniform base + lane*16
    __builtin_amdgcn_global_load_lds(
        (const __attribute__((address_space(1))) void*)g,
        (__attribute__((address_space(3))) void*)l, 16, 0, 0);
}

// ---------------------------------------------------------------------------
// fp32 -> bf16 elementwise (weights).
// ---------------------------------------------------------------------------
__global__ __launch_bounds__(256) void cvt_bf(
    const float* __restrict__ src, u16* __restrict__ dst, int n4)
{
    const int i = blockIdx.x * 256 + threadIdx.x;
    if (i < n4) {
        const float4 v = reinterpret_cast<const float4*>(src)[i];
        uint2 o;
        o.x = (u32)f2bf(v.x) | ((u32)f2bf(v.y) << 16);
        o.y = (u32)f2bf(v.z) | ((u32)f2bf(v.w) << 16);
        reinterpret_cast<uint2*>(dst)[i] = o;
    }
}

// ---------------------------------------------------------------------------
// x fp32 [b][512][196] -> XT bf16 [b][224][512] (pad rows garbage, masked
// downstream: EB=0 for m>=196, OT/out stores guarded for n>=196).
// ---------------------------------------------------------------------------
__global__ __launch_bounds__(256) void cvt_xT(
    const float* __restrict__ x, u16* __restrict__ XT)
{
    __shared__ float tile[64][65];
    const int t = threadIdx.x;
    const int jj = t & 63, ii = t >> 6;
    const int ct = blockIdx.x, ntb = blockIdx.y, b = blockIdx.z;
    const float* xb = x + ((size_t)b * DIM_ + ct * 64) * N_;
    const int n0 = ntb * 64;
    #pragma unroll
    for (int s = 0; s < 16; ++s) {
        const int i = ii + s * 4;
        const int n = n0 + jj;
        tile[i][jj] = (n < N_) ? xb[(size_t)i * N_ + n] : 0.f;
    }
    __syncthreads();
    u16* ot = XT + (size_t)b * NP_ * DIM_ + ct * 64;
    #pragma unroll
    for (int s = 0; s < 16; ++s) {
        const int nn = n0 + ii + s * 4;
        if (nn < N_) ot[(size_t)nn * DIM_ + jj] = f2bf(tile[jj][ii + s * 4]);
    }
}

// ---------------------------------------------------------------------------
// EB[h][208][224] = exp(bias[h][bidx[n][m]]) for n,m<196 else 0.
// ---------------------------------------------------------------------------
__global__ __launch_bounds__(256) void mk_eb(
    const float* __restrict__ biases, const int* __restrict__ bidx,
    float* __restrict__ EB)
{
    const int n = blockIdx.x, h = blockIdx.y;
    const int m = threadIdx.x;
    if (m < NP_) {
        float v = 0.f;
        if (n < N_ && m < N_) v = __expf(biases[h * N_ + bidx[n * N_ + m]]);
        EB[((size_t)h * NROW_ + n) * NP_ + m] = v;
    }
}

// ---------------------------------------------------------------------------
// m97-style 128x128 MFMA GEMM: C[M][28672] = W[M][512] . XT[28672][512]^T.
// grid (224 j-tiles, M/128 m-tiles), 256 thr = 2x2 waves, wave = 64x64
// (4x4 frags 16x16x32, acc 64 VGPR). BK=32: two 8 KB LDS tiles staged by
// global_load_lds width=16 (4 calls/wave/iter), 16 K-iters, 2-barrier loop.
// LDS slot map slot(row,chunk)=row*4+(chunk^((row>>1)&3)) via SOURCE chunk
// permutation (dest must be lane-contiguous) -> frag ds_read_b128 is 2-way
// bank-aliased = free (m136). r3 lesson: no waves_per_eu attribute.
// Epilogue QKV: qT/kT[b][h][n<=224][64] (8B stores), vS[b][h][d][224];
// pads stored unguarded -- EB=0 masks every pad contribution downstream.
// Epilogue proj: fp32 out[b][512][196], n guarded.
// ---------------------------------------------------------------------------
template<bool QKV>
__global__ __launch_bounds__(256) void gemm128(
    const u16* __restrict__ Bt, const u16* __restrict__ W,
    const float* __restrict__ bias,
    u16* __restrict__ o_q, u16* __restrict__ o_k, u16* __restrict__ o_v,
    float* __restrict__ o_f)
{
    __shared__ u16 As[128 * 32];
    __shared__ u16 Bs[128 * 32];
    const int t = threadIdx.x;
    const int wave = t >> 6, lane = t & 63;
    const int m16 = lane & 15, quad = lane >> 4;
    const int jt = blockIdx.x, mt = blockIdx.y;
    const int m0 = mt * 128, j0 = jt * 128;
    const int wy = wave >> 1, wx = wave & 1;     // wave tile: rows wy*64, cols wx*64

    // staging: call c = wave*2+cc fills slots [c*64, c*64+64); lane's source
    // row = c*16 + (lane>>2), source chunk = (lane&3) ^ ((lane>>3)&3).
    const int srow  = (lane >> 2);               // + c*16
    const int schnk = (lane & 3) ^ ((lane >> 3) & 3);
    const u16* gA = W  + (size_t)(m0 + wave * 32 + srow) * DIM_ + schnk * 8;
    const u16* gB = Bt + (size_t)(j0 + wave * 32 + srow) * DIM_ + schnk * 8;

    // frag read column: col = quad ^ ((m16>>1)&3); u16 offset row*32 + col*8
    const int rcol = (quad ^ ((m16 >> 1) & 3)) * 8;

    f32x4 acc[4][4];
    const f32x4 z4 = {0.f, 0.f, 0.f, 0.f};
    #pragma unroll
    for (int fi = 0; fi < 4; ++fi)
        #pragma unroll
        for (int fj = 0; fj < 4; ++fj) acc[fi][fj] = z4;

    for (int kt = 0; kt < 16; ++kt) {
        __syncthreads();                          // prior iter done reading LDS
        #pragma unroll
        for (int cc = 0; cc < 2; ++cc) {
            const int c = wave * 2 + cc;
            gload_lds16(gA + (size_t)(cc * 16) * DIM_ + kt * 32, As + c * 512);
            gload_lds16(gB + (size_t)(cc * 16) * DIM_ + kt * 32, Bs + c * 512);
        }
        __syncthreads();                          // vmcnt(0) drain -> LDS visible
        bf16x8 af[4], bf[4];
        #pragma unroll
        for (int fi = 0; fi < 4; ++fi)
            af[fi] = *reinterpret_cast<const bf16x8*>(As + (wy * 64 + fi * 16 + m16) * 32 + rcol);
        #pragma unroll
        for (int fj = 0; fj < 4; ++fj)
            bf[fj] = *reinterpret_cast<const bf16x8*>(Bs + (wx * 64 + fj * 16 + m16) * 32 + rcol);
        #pragma unroll
        for (int fi = 0; fi < 4; ++fi)
            #pragma unroll
            for (int fj = 0; fj < 4; ++fj)
                acc[fi][fj] = __builtin_amdgcn_mfma_f32_16x16x32_bf16(af[fi], bf[fj], acc[fi][fj], 0, 0, 0);
    }

    // ---- epilogue ----
    const int mbase = m0 + wy * 64;              // 64-aligned -> part,h wave-uniform
    float bb[4][4];
    #pragma unroll
    for (int fi = 0; fi < 4; ++fi)
        #pragma unroll
        for (int r = 0; r < 4; ++r) bb[fi][r] = bias[mbase + fi * 16 + quad * 4 + r];

    if (QKV) {
        const int part = mbase >> 9;             // 0=q 1=k 2=v
        const int h = (mbase & 511) >> 6;
        #pragma unroll
        for (int fj = 0; fj < 4; ++fj) {
            const int j = j0 + wx * 64 + fj * 16 + m16;
            const u32 b = (u32)j / 224u;
            const int n = j - (int)b * 224;
            if (part < 2) {                      // q,k -> [b][h][n][64], 8B packed
                u16* base = (part == 0 ? o_q : o_k) + (((size_t)b * HEADS_ + h) * NP_ + n) * HD_;
                #pragma unroll
                for (int fi = 0; fi < 4; ++fi) {
                    const int d0 = fi * 16 + quad * 4;
                    uint2 pk;
                    pk.x = (u32)f2bf(acc[fi][fj][0] + bb[fi][0]) | ((u32)f2bf(acc[fi][fj][1] + bb[fi][1]) << 16);
                    pk.y = (u32)f2bf(acc[fi][fj][2] + bb[fi][2]) | ((u32)f2bf(acc[fi][fj][3] + bb[fi][3]) << 16);
                    *reinterpret_cast<uint2*>(base + d0) = pk;
                }
            } else {                             // v -> [b][h][d][224], 2B stores
                u16* vb = o_v + (((size_t)b * HEADS_ + h) * HD_) * NP_ + n;
                #pragma unroll
                for (int fi = 0; fi < 4; ++fi) {
                    const int d0 = fi * 16 + quad * 4;
                    #pragma unroll
                    for (int r = 0; r < 4; ++r)
                        vb[(size_t)(d0 + r) * NP_] = f2bf(acc[fi][fj][r] + bb[fi][r]);
                }
            }
        }
    } else {                                     // proj: fp32 out[b][512][196]
        #pragma unroll
        for (int fj = 0; fj < 4; ++fj) {
            const int j = j0 + wx * 64 + fj * 16 + m16;
            const u32 b = (u32)j / 224u;
            const int n = j - (int)b * 224;
            if (n < N_) {
                float* ob = o_f + (size_t)b * BSTRIDE + n;
                #pragma unroll
                for (int fi = 0; fi < 4; ++fi) {
                    const int r0 = mbase + fi * 16 + quad * 4;
                    #pragma unroll
                    for (int r = 0; r < 4; ++r)
                        ob[(size_t)(r0 + r) * N_] = acc[fi][fj][r] + bb[fi][r];
                }
            }
        }
    }
}

// ---------------------------------------------------------------------------
// MFMA attention per (b,h), 8 waves (512 thr). r6: K and V staged in LDS once
// per block (was: every wave re-read full K+V from global per nt-tile ->
// L1/L2 thrash, FETCH 408 MB vs 90 MB ideal, MfmaUtil 2% = latency-bound).
//   Ks[224][64] u16, chunk-XOR swizzled: 16B chunk ch of row r stored at
//     ch^(r&7) -> stride-128B ds_read_b128 frag reads hit the 8-pass minimum
//     (no extra conflicts). Read addr: ch_want = ks*4+quad, xor with m16&7.
//   Vs[64][232] u16, +8 u16 row pad (same trick as P) -> b128 reads minimal.
//   P[8][16*232] per-wave (unchanged math).
// LDS total 117.8 KB -> 1 block/CU, 8 waves = 2/SIMD; 1024 blocks = 4 rounds.
// All arithmetic identical to r5 (mx over all 14 mtiles incl. pads, EB=0
// masks pad m; OT stores guarded n<196).
// ---------------------------------------------------------------------------
__global__ __launch_bounds__(512) void attn_mfma(
    const u16* __restrict__ qT, const u16* __restrict__ kT,
    const u16* __restrict__ vS, const float* __restrict__ EB,
    u16* __restrict__ OT)
{
    __shared__ u16 Ks[224 * 64];        // 28.7 KB, chunk-XOR swizzled
    __shared__ u16 Vs[64 * 232];        // 29.7 KB, row-padded
    __shared__ u16 P[8][16 * 232];      // 59.4 KB
    const int t = threadIdx.x;
    const int wave = t >> 6, lane = t & 63;
    const int m16 = lane & 15, quad = lane >> 4;
    const int b = blockIdx.x, h = blockIdx.y;
    const u16* qTb = qT + ((size_t)b * HEADS_ + h) * (NP_ * HD_);
    const u16* kTb = kT + ((size_t)b * HEADS_ + h) * (NP_ * HD_);
    const u16* vb  = vS + ((size_t)b * HEADS_ + h) * (HD_ * NP_);
    const float* ebh = EB + (size_t)h * NROW_ * NP_;
    u16* Pw = P[wave];
    u16* otb = OT + (size_t)b * NP_ * DIM_ + h * HD_;
    const f32x4 z4 = {0.f, 0.f, 0.f, 0.f};

    // ---- stage K: 224 rows x 8 chunks(16B) = 1792 chunks over 512 thr ----
    #pragma unroll
    for (int i = 0; i < 4; ++i) {
        const int c = t + i * 512;
        if (c < 1792) {
            const int row = c >> 3, ch = c & 7;
            const bf16x8 d = *reinterpret_cast<const bf16x8*>(kTb + row * HD_ + ch * 8);
            *reinterpret_cast<bf16x8*>(Ks + row * 64 + ((ch ^ (row & 7)) * 8)) = d;
        }
    }
    // ---- stage V: 64 rows x 28 chunks(16B) = 1792 chunks, repack to 232 ----
    #pragma unroll
    for (int i = 0; i < 4; ++i) {
        const int c = t + i * 512;
        if (c < 1792) {
            const u32 row = (u32)c / 28u;
            const int ch = c - (int)row * 28;
            const bf16x8 d = *reinterpret_cast<const bf16x8*>(vb + (size_t)row * NP_ + ch * 8);
            *reinterpret_cast<bf16x8*>(Vs + row * 232 + ch * 8) = d;
        }
    }
    __syncthreads();

    for (int nt = wave; nt < 13; nt += 8) {
        f32x4 s[14];
        #pragma unroll
        for (int mt = 0; mt < 14; ++mt) s[mt] = z4;
        #pragma unroll
        for (int ks = 0; ks < 2; ++ks) {
            const bf16x8 a = *reinterpret_cast<const bf16x8*>(
                qTb + (size_t)(nt * 16 + m16) * HD_ + ks * 32 + quad * 8);
            const int ch = ((ks * 4 + quad) ^ (m16 & 7)) * 8;   // K swizzle inverse
            #pragma unroll
            for (int mtile = 0; mtile < 14; ++mtile) {
                const bf16x8 bf = *reinterpret_cast<const bf16x8*>(
                    Ks + (mtile * 16 + m16) * 64 + ch);
                s[mtile] = __builtin_amdgcn_mfma_f32_16x16x32_bf16(a, bf, s[mtile], 0, 0, 0);
            }
        }
        float mx[4] = {-INFINITY, -INFINITY, -INFINITY, -INFINITY};
        #pragma unroll
        for (int mt = 0; mt < 14; ++mt)
            #pragma unroll
            for (int r = 0; r < 4; ++r) mx[r] = fmaxf(mx[r], s[mt][r]);
        #pragma unroll
        for (int off = 1; off < 16; off <<= 1)
            #pragma unroll
            for (int r = 0; r < 4; ++r) mx[r] = fmaxf(mx[r], __shfl_xor(mx[r], off, 64));
        #pragma unroll
        for (int r = 0; r < 4; ++r) mx[r] *= SCALE_;

        const float* ebn = ebh + (size_t)(nt * 16 + quad * 4) * NP_ + m16;
        float sum[4] = {0.f, 0.f, 0.f, 0.f};
        #pragma unroll
        for (int mt = 0; mt < 14; ++mt) {
            #pragma unroll
            for (int r = 0; r < 4; ++r) {
                const float e = __expf(fmaf(s[mt][r], SCALE_, -mx[r])) * ebn[(size_t)r * NP_ + mt * 16];
                s[mt][r] = e;
                sum[r] += e;
            }
        }
        #pragma unroll
        for (int off = 1; off < 16; off <<= 1)
            #pragma unroll
            for (int r = 0; r < 4; ++r) sum[r] += __shfl_xor(sum[r], off, 64);
        float inv[4];
        #pragma unroll
        for (int r = 0; r < 4; ++r) inv[r] = 1.f / sum[r];

        #pragma unroll
        for (int mt = 0; mt < 14; ++mt)
            #pragma unroll
            for (int r = 0; r < 4; ++r)
                Pw[(quad * 4 + r) * 232 + mt * 16 + m16] = f2bf(s[mt][r] * inv[r]);

        f32x4 o[4];
        #pragma unroll
        for (int dt = 0; dt < 4; ++dt) o[dt] = z4;
        #pragma unroll
        for (int ks = 0; ks < 7; ++ks) {
            const bf16x8 a = *reinterpret_cast<const bf16x8*>(Pw + m16 * 232 + ks * 32 + quad * 8);
            #pragma unroll
            for (int dt = 0; dt < 4; ++dt) {
                const bf16x8 bf = *reinterpret_cast<const bf16x8*>(
                    Vs + (dt * 16 + m16) * 232 + ks * 32 + quad * 8);
                o[dt] = __builtin_amdgcn_mfma_f32_16x16x32_bf16(a, bf, o[dt], 0, 0, 0);
            }
        }
        #pragma unroll
        for (int r = 0; r < 4; ++r) {
            const int n = nt * 16 + quad * 4 + r;
            if (n < N_) {
                #pragma unroll
                for (int dt = 0; dt < 4; ++dt)
                    otb[(size_t)n * DIM_ + dt * 16 + m16] = f2bf(o[dt][r]);
            }
        }
    }
}

extern "C" void kernel_launch(void* const* d_in, const int* in_sizes, int n_in,
                              void* d_out, int out_size, void* d_ws, size_t ws_size,
                              hipStream_t stream) {
    const float* x      = (const float*)d_in[0];
    const float* qkv_w  = (const float*)d_in[1];
    const float* qkv_b  = (const float*)d_in[2];
    const float* proj_w = (const float*)d_in[3];
    const float* proj_b = (const float*)d_in[4];
    const float* biases = (const float*)d_in[5];
    const int*   bidx   = (const int*)d_in[6];
    float* out = (float*)d_out;

    // ws layout (~92 MB; 103 MB proven safe):
    char* w = (char*)d_ws;
    u16* XT  = (u16*)w; w += (size_t)B_ * NP_ * DIM_ * 2;            // 29.4 MB (reused as OT)
    u16* qTw = (u16*)w; w += (size_t)B_ * HEADS_ * NP_ * HD_ * 2;    // 29.4 MB
    u16* vSw = (u16*)w; w += (size_t)B_ * HEADS_ * HD_ * NP_ * 2;    // 29.4 MB
    float* EB = (float*)w; w += (size_t)HEADS_ * NROW_ * NP_ * 4;    // 1.5 MB
    u16* wq  = (u16*)w; w += (size_t)3 * DIM_ * DIM_ * 2;            // 1.6 MB
    u16* wpj = (u16*)w;                                              // 0.5 MB
    u16* kTw = (u16*)d_out;                                          // kT parked in d_out

    cvt_bf<<<(3 * DIM_ * DIM_ / 4 + 255) / 256, 256, 0, stream>>>(qkv_w, wq, 3 * DIM_ * DIM_ / 4);
    cvt_bf<<<(DIM_ * DIM_ / 4 + 255) / 256, 256, 0, stream>>>(proj_w, wpj, DIM_ * DIM_ / 4);
    cvt_xT<<<dim3(8, 4, B_), 256, 0, stream>>>(x, XT);
    mk_eb<<<dim3(NROW_, HEADS_), 256, 0, stream>>>(biases, bidx, EB);
    gemm128<true><<<dim3(J_ / 128, 12), 256, 0, stream>>>(XT, wq, qkv_b, qTw, kTw, vSw, nullptr);
    attn_mfma<<<dim3(B_, HEADS_), 512, 0, stream>>>(qTw, kTw, vSw, EB, XT);
    gemm128<false><<<dim3(J_ / 128, 4), 256, 0, stream>>>(XT, wpj, proj_b, nullptr, nullptr, nullptr, out);
}

// Round 3
// 276.493 us; speedup vs baseline: 1.7937x; 1.0503x over previous
//
#include <hip/hip_runtime.h>
#include <hip/hip_bf16.h>
#include <math.h>

#define B_     128
#define DIM_   512
#define HEADS_ 8
#define HD_    64
#define N_     196
#define NP_    224            // padded n (14 tiles of 16)
#define NROW_  208            // padded n rows (13 tiles of 16) for EB
#define SCALE_ 0.125f
#define BSTRIDE (DIM_ * N_)
#define J_     (B_ * NP_)     // 28672 GEMM columns (b*224+n)

typedef unsigned short u16;
typedef unsigned int   u32;
typedef __attribute__((ext_vector_type(8))) short bf16x8;   // 8 bf16 = 4 VGPRs
typedef __attribute__((ext_vector_type(4))) float f32x4;

__device__ __forceinline__ u16 f2bf(float f) {              // RNE fp32->bf16
    u32 u = __float_as_uint(f);
    return (u16)((u + 0x7fffu + ((u >> 16) & 1u)) >> 16);
}
__device__ __forceinline__ void gload_lds16(const u16* g, u16* l) {
    // async global->LDS, 16B/lane; LDS dest = wave-uniform base + lane*16
    __builtin_amdgcn_global_load_lds(
        (const __attribute__((address_space(1))) void*)g,
        (__attribute__((address_space(3))) void*)l, 16, 0, 0);
}

// ---------------------------------------------------------------------------
// fp32 -> bf16 elementwise, two tensors in one launch (y=0: qkv_w, y=1: proj).
// ---------------------------------------------------------------------------
__global__ __launch_bounds__(256) void cvt_bf2(
    const float* __restrict__ a, u16* __restrict__ da, int n4a,
    const float* __restrict__ b, u16* __restrict__ db, int n4b)
{
    const int i = blockIdx.x * 256 + threadIdx.x;
    const float* src = blockIdx.y ? b : a;
    u16* dst = blockIdx.y ? db : da;
    const int n4 = blockIdx.y ? n4b : n4a;
    if (i < n4) {
        const float4 v = reinterpret_cast<const float4*>(src)[i];
        uint2 o;
        o.x = (u32)f2bf(v.x) | ((u32)f2bf(v.y) << 16);
        o.y = (u32)f2bf(v.z) | ((u32)f2bf(v.w) << 16);
        reinterpret_cast<uint2*>(dst)[i] = o;
    }
}

// ---------------------------------------------------------------------------
// x fp32 [b][512][196] -> XT bf16 [b][224][512] (pad rows garbage, masked
// downstream: EB=0 for m>=196, OT/out stores guarded for n>=196).
// ---------------------------------------------------------------------------
__global__ __launch_bounds__(256) void cvt_xT(
    const float* __restrict__ x, u16* __restrict__ XT)
{
    __shared__ float tile[64][65];
    const int t = threadIdx.x;
    const int jj = t & 63, ii = t >> 6;
    const int ct = blockIdx.x, ntb = blockIdx.y, b = blockIdx.z;
    const float* xb = x + ((size_t)b * DIM_ + ct * 64) * N_;
    const int n0 = ntb * 64;
    #pragma unroll
    for (int s = 0; s < 16; ++s) {
        const int i = ii + s * 4;
        const int n = n0 + jj;
        tile[i][jj] = (n < N_) ? xb[(size_t)i * N_ + n] : 0.f;
    }
    __syncthreads();
    u16* ot = XT + (size_t)b * NP_ * DIM_ + ct * 64;
    #pragma unroll
    for (int s = 0; s < 16; ++s) {
        const int nn = n0 + ii + s * 4;
        if (nn < N_) ot[(size_t)nn * DIM_ + jj] = f2bf(tile[jj][ii + s * 4]);
    }
}

// ---------------------------------------------------------------------------
// EB[h][208][224] = exp(bias[h][bidx[n][m]]) for n,m<196 else 0.
// ---------------------------------------------------------------------------
__global__ __launch_bounds__(256) void mk_eb(
    const float* __restrict__ biases, const int* __restrict__ bidx,
    float* __restrict__ EB)
{
    const int n = blockIdx.x, h = blockIdx.y;
    const int m = threadIdx.x;
    if (m < NP_) {
        float v = 0.f;
        if (n < N_ && m < N_) v = __expf(biases[h * N_ + bidx[n * N_ + m]]);
        EB[((size_t)h * NROW_ + n) * NP_ + m] = v;
    }
}

// ---------------------------------------------------------------------------
// 128x128 MFMA GEMM: C[M][28672] = W[M][512] . XT[28672][512]^T.
// r8 == r7 resubmit (container infra failure, no kernel verdict):
// (1) double-buffered prefetch K-loop (T3-minimum): stage kt+1 into buf^1
// before computing kt; ONE barrier/iter whose implicit vmcnt(0) drain lands
// AFTER ds_read+MFMA -> load latency hidden (was: serial 2-barrier
// stage-wait, full L2 latency exposed 16x/block, MfmaUtil 20%).
// Race-free: reads of buf[cur] follow the barrier that drained its staging;
// prefetch targets only buf[cur^1] whose readers finished pre-barrier.
// (2) 1-D grid, mt-fastest + bijective XCD swizzle (nwg%8==0): each XCD gets
// contiguous jt-chunk with all mt -> XT panel fetched by one XCD, 12x L2
// reuse (was 87 MB fetch vs 30 ideal).
// LDS slot map slot(row,chunk)=row*4+(chunk^((row>>1)&3)) via SOURCE chunk
// permutation (dest must be lane-contiguous) -> frag ds_read_b128 is 2-way
// bank-aliased = free (m136). r3 lesson: no waves_per_eu attribute.
// Epilogue QKV: qT/kT[b][h][n<=224][64] (8B stores), vS[b][h][d][224];
// pads stored unguarded -- EB=0 masks every pad contribution downstream.
// Epilogue proj: fp32 out[b][512][196], n guarded.
// ---------------------------------------------------------------------------
template<bool QKV>
__global__ __launch_bounds__(256) void gemm128(
    const u16* __restrict__ Bt, const u16* __restrict__ W,
    const float* __restrict__ bias,
    u16* __restrict__ o_q, u16* __restrict__ o_k, u16* __restrict__ o_v,
    float* __restrict__ o_f)
{
    __shared__ u16 As[2][128 * 32];
    __shared__ u16 Bs[2][128 * 32];
    const int t = threadIdx.x;
    const int wave = t >> 6, lane = t & 63;
    const int m16 = lane & 15, quad = lane >> 4;

    constexpr int MT  = QKV ? 12 : 4;
    constexpr int NWG = (J_ / 128) * MT;
    const int bid = blockIdx.x;
    const int swz = (bid & 7) * (NWG / 8) + (bid >> 3);   // bijective XCD swizzle
    const int mt = swz % MT;                               // mt fastest
    const int jt = swz / MT;
    const int m0 = mt * 128, j0 = jt * 128;
    const int wy = wave >> 1, wx = wave & 1;     // wave tile: rows wy*64, cols wx*64

    // staging: call c = wave*2+cc fills slots [c*64, c*64+64); lane's source
    // row = c*16 + (lane>>2), source chunk = (lane&3) ^ ((lane>>3)&3).
    const int srow  = (lane >> 2);               // + c*16
    const int schnk = (lane & 3) ^ ((lane >> 3) & 3);
    const u16* gA = W  + (size_t)(m0 + wave * 32 + srow) * DIM_ + schnk * 8;
    const u16* gB = Bt + (size_t)(j0 + wave * 32 + srow) * DIM_ + schnk * 8;

    // frag read column: col = quad ^ ((m16>>1)&3); u16 offset row*32 + col*8
    const int rcol = (quad ^ ((m16 >> 1) & 3)) * 8;

    f32x4 acc[4][4];
    const f32x4 z4 = {0.f, 0.f, 0.f, 0.f};
    #pragma unroll
    for (int fi = 0; fi < 4; ++fi)
        #pragma unroll
        for (int fj = 0; fj < 4; ++fj) acc[fi][fj] = z4;

    // prologue: stage kt=0 into buf 0
    #pragma unroll
    for (int cc = 0; cc < 2; ++cc) {
        const int c = wave * 2 + cc;
        gload_lds16(gA + (size_t)(cc * 16) * DIM_, As[0] + c * 512);
        gload_lds16(gB + (size_t)(cc * 16) * DIM_, Bs[0] + c * 512);
    }
    #pragma unroll
    for (int kt = 0; kt < 16; ++kt) {
        const int cur = kt & 1;
        __syncthreads();      // vmcnt(0) drain: buf[cur] staged & visible;
                              // all waves done reading buf[cur^1]
        if (kt < 15) {        // prefetch kt+1 into the buffer just released
            #pragma unroll
            for (int cc = 0; cc < 2; ++cc) {
                const int c = wave * 2 + cc;
                gload_lds16(gA + (size_t)(cc * 16) * DIM_ + (kt + 1) * 32, As[cur ^ 1] + c * 512);
                gload_lds16(gB + (size_t)(cc * 16) * DIM_ + (kt + 1) * 32, Bs[cur ^ 1] + c * 512);
            }
        }
        bf16x8 af[4], bf[4];
        #pragma unroll
        for (int fi = 0; fi < 4; ++fi)
            af[fi] = *reinterpret_cast<const bf16x8*>(As[cur] + (wy * 64 + fi * 16 + m16) * 32 + rcol);
        #pragma unroll
        for (int fj = 0; fj < 4; ++fj)
            bf[fj] = *reinterpret_cast<const bf16x8*>(Bs[cur] + (wx * 64 + fj * 16 + m16) * 32 + rcol);
        #pragma unroll
        for (int fi = 0; fi < 4; ++fi)
            #pragma unroll
            for (int fj = 0; fj < 4; ++fj)
                acc[fi][fj] = __builtin_amdgcn_mfma_f32_16x16x32_bf16(af[fi], bf[fj], acc[fi][fj], 0, 0, 0);
    }

    // ---- epilogue ----
    const int mbase = m0 + wy * 64;              // 64-aligned -> part,h wave-uniform
    float bb[4][4];
    #pragma unroll
    for (int fi = 0; fi < 4; ++fi)
        #pragma unroll
        for (int r = 0; r < 4; ++r) bb[fi][r] = bias[mbase + fi * 16 + quad * 4 + r];

    if (QKV) {
        const int part = mbase >> 9;             // 0=q 1=k 2=v
        const int h = (mbase & 511) >> 6;
        #pragma unroll
        for (int fj = 0; fj < 4; ++fj) {
            const int j = j0 + wx * 64 + fj * 16 + m16;
            const u32 b = (u32)j / 224u;
            const int n = j - (int)b * 224;
            if (part < 2) {                      // q,k -> [b][h][n][64], 8B packed
                u16* base = (part == 0 ? o_q : o_k) + (((size_t)b * HEADS_ + h) * NP_ + n) * HD_;
                #pragma unroll
                for (int fi = 0; fi < 4; ++fi) {
                    const int d0 = fi * 16 + quad * 4;
                    uint2 pk;
                    pk.x = (u32)f2bf(acc[fi][fj][0] + bb[fi][0]) | ((u32)f2bf(acc[fi][fj][1] + bb[fi][1]) << 16);
                    pk.y = (u32)f2bf(acc[fi][fj][2] + bb[fi][2]) | ((u32)f2bf(acc[fi][fj][3] + bb[fi][3]) << 16);
                    *reinterpret_cast<uint2*>(base + d0) = pk;
                }
            } else {                             // v -> [b][h][d][224], 2B stores
                u16* vb = o_v + (((size_t)b * HEADS_ + h) * HD_) * NP_ + n;
                #pragma unroll
                for (int fi = 0; fi < 4; ++fi) {
                    const int d0 = fi * 16 + quad * 4;
                    #pragma unroll
                    for (int r = 0; r < 4; ++r)
                        vb[(size_t)(d0 + r) * NP_] = f2bf(acc[fi][fj][r] + bb[fi][r]);
                }
            }
        }
    } else {                                     // proj: fp32 out[b][512][196]
        #pragma unroll
        for (int fj = 0; fj < 4; ++fj) {
            const int j = j0 + wx * 64 + fj * 16 + m16;
            const u32 b = (u32)j / 224u;
            const int n = j - (int)b * 224;
            if (n < N_) {
                float* ob = o_f + (size_t)b * BSTRIDE + n;
                #pragma unroll
                for (int fi = 0; fi < 4; ++fi) {
                    const int r0 = mbase + fi * 16 + quad * 4;
                    #pragma unroll
                    for (int r = 0; r < 4; ++r)
                        ob[(size_t)(r0 + r) * N_] = acc[fi][fj][r] + bb[fi][r];
                }
            }
        }
    }
}

// ---------------------------------------------------------------------------
// MFMA attention per (b,h), 8 waves (512 thr). K and V staged in LDS once
// per block.
//   Ks[224][64] u16, chunk-XOR swizzled: 16B chunk ch of row r stored at
//     ch^(r&7) -> stride-128B ds_read_b128 frag reads hit the 8-pass minimum.
//   Vs[64][232] u16, +8 u16 row pad -> b128 reads minimal.
//   P[8][16*232] per-wave.
// LDS total 117.8 KB -> 1 block/CU, 8 waves = 2/SIMD; 1024 blocks = 4 rounds.
// mx over all 14 mtiles incl. pads, EB=0 masks pad m; OT stores guarded n<196.
// ---------------------------------------------------------------------------
__global__ __launch_bounds__(512) void attn_mfma(
    const u16* __restrict__ qT, const u16* __restrict__ kT,
    const u16* __restrict__ vS, const float* __restrict__ EB,
    u16* __restrict__ OT)
{
    __shared__ u16 Ks[224 * 64];        // 28.7 KB, chunk-XOR swizzled
    __shared__ u16 Vs[64 * 232];        // 29.7 KB, row-padded
    __shared__ u16 P[8][16 * 232];      // 59.4 KB
    const int t = threadIdx.x;
    const int wave = t >> 6, lane = t & 63;
    const int m16 = lane & 15, quad = lane >> 4;
    const int b = blockIdx.x, h = blockIdx.y;
    const u16* qTb = qT + ((size_t)b * HEADS_ + h) * (NP_ * HD_);
    const u16* kTb = kT + ((size_t)b * HEADS_ + h) * (NP_ * HD_);
    const u16* vb  = vS + ((size_t)b * HEADS_ + h) * (HD_ * NP_);
    const float* ebh = EB + (size_t)h * NROW_ * NP_;
    u16* Pw = P[wave];
    u16* otb = OT + (size_t)b * NP_ * DIM_ + h * HD_;
    const f32x4 z4 = {0.f, 0.f, 0.f, 0.f};

    // ---- stage K: 224 rows x 8 chunks(16B) = 1792 chunks over 512 thr ----
    #pragma unroll
    for (int i = 0; i < 4; ++i) {
        const int c = t + i * 512;
        if (c < 1792) {
            const int row = c >> 3, ch = c & 7;
            const bf16x8 d = *reinterpret_cast<const bf16x8*>(kTb + row * HD_ + ch * 8);
            *reinterpret_cast<bf16x8*>(Ks + row * 64 + ((ch ^ (row & 7)) * 8)) = d;
        }
    }
    // ---- stage V: 64 rows x 28 chunks(16B) = 1792 chunks, repack to 232 ----
    #pragma unroll
    for (int i = 0; i < 4; ++i) {
        const int c = t + i * 512;
        if (c < 1792) {
            const u32 row = (u32)c / 28u;
            const int ch = c - (int)row * 28;
            const bf16x8 d = *reinterpret_cast<const bf16x8*>(vb + (size_t)row * NP_ + ch * 8);
            *reinterpret_cast<bf16x8*>(Vs + row * 232 + ch * 8) = d;
        }
    }
    __syncthreads();

    for (int nt = wave; nt < 13; nt += 8) {
        f32x4 s[14];
        #pragma unroll
        for (int mt = 0; mt < 14; ++mt) s[mt] = z4;
        #pragma unroll
        for (int ks = 0; ks < 2; ++ks) {
            const bf16x8 a = *reinterpret_cast<const bf16x8*>(
                qTb + (size_t)(nt * 16 + m16) * HD_ + ks * 32 + quad * 8);
            const int ch = ((ks * 4 + quad) ^ (m16 & 7)) * 8;   // K swizzle inverse
            #pragma unroll
            for (int mtile = 0; mtile < 14; ++mtile) {
                const bf16x8 bf = *reinterpret_cast<const bf16x8*>(
                    Ks + (mtile * 16 + m16) * 64 + ch);
                s[mtile] = __builtin_amdgcn_mfma_f32_16x16x32_bf16(a, bf, s[mtile], 0, 0, 0);
            }
        }
        float mx[4] = {-INFINITY, -INFINITY, -INFINITY, -INFINITY};
        #pragma unroll
        for (int mt = 0; mt < 14; ++mt)
            #pragma unroll
            for (int r = 0; r < 4; ++r) mx[r] = fmaxf(mx[r], s[mt][r]);
        #pragma unroll
        for (int off = 1; off < 16; off <<= 1)
            #pragma unroll
            for (int r = 0; r < 4; ++r) mx[r] = fmaxf(mx[r], __shfl_xor(mx[r], off, 64));
        #pragma unroll
        for (int r = 0; r < 4; ++r) mx[r] *= SCALE_;

        const float* ebn = ebh + (size_t)(nt * 16 + quad * 4) * NP_ + m16;
        float sum[4] = {0.f, 0.f, 0.f, 0.f};
        #pragma unroll
        for (int mt = 0; mt < 14; ++mt) {
            #pragma unroll
            for (int r = 0; r < 4; ++r) {
                const float e = __expf(fmaf(s[mt][r], SCALE_, -mx[r])) * ebn[(size_t)r * NP_ + mt * 16];
                s[mt][r] = e;
                sum[r] += e;
            }
        }
        #pragma unroll
        for (int off = 1; off < 16; off <<= 1)
            #pragma unroll
            for (int r = 0; r < 4; ++r) sum[r] += __shfl_xor(sum[r], off, 64);
        float inv[4];
        #pragma unroll
        for (int r = 0; r < 4; ++r) inv[r] = 1.f / sum[r];

        #pragma unroll
        for (int mt = 0; mt < 14; ++mt)
            #pragma unroll
            for (int r = 0; r < 4; ++r)
                Pw[(quad * 4 + r) * 232 + mt * 16 + m16] = f2bf(s[mt][r] * inv[r]);

        f32x4 o[4];
        #pragma unroll
        for (int dt = 0; dt < 4; ++dt) o[dt] = z4;
        #pragma unroll
        for (int ks = 0; ks < 7; ++ks) {
            const bf16x8 a = *reinterpret_cast<const bf16x8*>(Pw + m16 * 232 + ks * 32 + quad * 8);
            #pragma unroll
            for (int dt = 0; dt < 4; ++dt) {
                const bf16x8 bf = *reinterpret_cast<const bf16x8*>(
                    Vs + (dt * 16 + m16) * 232 + ks * 32 + quad * 8);
                o[dt] = __builtin_amdgcn_mfma_f32_16x16x32_bf16(a, bf, o[dt], 0, 0, 0);
            }
        }
        #pragma unroll
        for (int r = 0; r < 4; ++r) {
            const int n = nt * 16 + quad * 4 + r;
            if (n < N_) {
                #pragma unroll
                for (int dt = 0; dt < 4; ++dt)
                    otb[(size_t)n * DIM_ + dt * 16 + m16] = f2bf(o[dt][r]);
            }
        }
    }
}

extern "C" void kernel_launch(void* const* d_in, const int* in_sizes, int n_in,
                              void* d_out, int out_size, void* d_ws, size_t ws_size,
                              hipStream_t stream) {
    const float* x      = (const float*)d_in[0];
    const float* qkv_w  = (const float*)d_in[1];
    const float* qkv_b  = (const float*)d_in[2];
    const float* proj_w = (const float*)d_in[3];
    const float* proj_b = (const float*)d_in[4];
    const float* biases = (const float*)d_in[5];
    const int*   bidx   = (const int*)d_in[6];
    float* out = (float*)d_out;

    // ws layout (~92 MB; 103 MB proven safe):
    char* w = (char*)d_ws;
    u16* XT  = (u16*)w; w += (size_t)B_ * NP_ * DIM_ * 2;            // 29.4 MB (reused as OT)
    u16* qTw = (u16*)w; w += (size_t)B_ * HEADS_ * NP_ * HD_ * 2;    // 29.4 MB
    u16* vSw = (u16*)w; w += (size_t)B_ * HEADS_ * HD_ * NP_ * 2;    // 29.4 MB
    float* EB = (float*)w; w += (size_t)HEADS_ * NROW_ * NP_ * 4;    // 1.5 MB
    u16* wq  = (u16*)w; w += (size_t)3 * DIM_ * DIM_ * 2;            // 1.6 MB
    u16* wpj = (u16*)w;                                              // 0.5 MB
    u16* kTw = (u16*)d_out;                                          // kT parked in d_out

    cvt_bf2<<<dim3(768, 2), 256, 0, stream>>>(qkv_w, wq, 3 * DIM_ * DIM_ / 4,
                                              proj_w, wpj, DIM_ * DIM_ / 4);
    cvt_xT<<<dim3(8, 4, B_), 256, 0, stream>>>(x, XT);
    mk_eb<<<dim3(NROW_, HEADS_), 256, 0, stream>>>(biases, bidx, EB);
    gemm128<true><<<dim3((J_ / 128) * 12), 256, 0, stream>>>(XT, wq, qkv_b, qTw, kTw, vSw, nullptr);
    attn_mfma<<<dim3(B_, HEADS_), 512, 0, stream>>>(qTw, kTw, vSw, EB, XT);
    gemm128<false><<<dim3((J_ / 128) * 4), 256, 0, stream>>>(XT, wpj, proj_b, nullptr, nullptr, nullptr, out);
}